// Round 1
// baseline (436.233 us; speedup 1.0000x reference)
//
#include <hip/hip_runtime.h>
#include <stdint.h>

// MultiHeadAttention: x(4,2048,1024) fp32; W_qkv(3072,1024); b_qkv(3072); W_o(1024,1024); b_o(1024)
// Reference does h.reshape(B,16,S,192) DIRECTLY (no transpose):
//   h[b,hh,ss,cc] = linear[b, s_orig = hh*128 + ss/16, j = (ss%16)*192 + cc]
// Pipeline: cvt(fp32->bf16) -> gemm_bt<QKV scatter> -> flash attn -> gemm_bt<out fp32>
// Workspace: 72 MiB (Ob aliases xb region — xb dead after gemm1).

typedef __attribute__((ext_vector_type(8))) short short8;
typedef __attribute__((ext_vector_type(4))) short short4v;
typedef __attribute__((ext_vector_type(4))) float f32x4;

#define B_SZ 4
#define S_SZ 2048
#define H_N 16
#define DK 64
#define IN_DIM 1024
#define QKV_DIM 3072
#define MODEL 1024
#define M_ROWS (B_SZ * S_SZ)   // 8192

__device__ __forceinline__ short f2bf(float f) {
    union { float f; uint32_t u; } v; v.f = f;
    uint32_t r = v.u + 0x7FFFu + ((v.u >> 16) & 1u);
    return (short)(r >> 16);
}

__device__ __forceinline__ void gld_lds16(const void* g, void* l) {
    __builtin_amdgcn_global_load_lds(
        (const __attribute__((address_space(1))) void*)g,
        (__attribute__((address_space(3))) void*)l, 16, 0, 0);
}

// ---------------- fp32 -> bf16 conversion of x, W_qkv, W_o ----------------
__global__ __launch_bounds__(256) void cvt_kernel(
    const float* __restrict__ x, const float* __restrict__ wq,
    const float* __restrict__ wo, short* __restrict__ xb,
    short* __restrict__ wqb, short* __restrict__ wob) {
    const int NX = M_ROWS * IN_DIM / 4;     // 2097152
    const int NQ = QKV_DIM * IN_DIM / 4;    // 786432
    const int NO = MODEL * IN_DIM / 4;      // 262144
    const int total = NX + NQ + NO;
    for (int i = blockIdx.x * blockDim.x + threadIdx.x; i < total;
         i += gridDim.x * blockDim.x) {
        const f32x4* src; short4v* dst; int j;
        if (i < NX)           { src = (const f32x4*)x;  dst = (short4v*)xb;  j = i; }
        else if (i < NX + NQ) { src = (const f32x4*)wq; dst = (short4v*)wqb; j = i - NX; }
        else                  { src = (const f32x4*)wo; dst = (short4v*)wob; j = i - NX - NQ; }
        f32x4 v = src[j];
        short4v o;
        o[0] = f2bf(v[0]); o[1] = f2bf(v[1]); o[2] = f2bf(v[2]); o[3] = f2bf(v[3]);
        dst[j] = o;
    }
}

// ---------------- GEMM C = A(MxK) * B(NxK)^T + bias  (bf16 in, m97-style) ----------------
// MODE 0: scatter epilogue into Q/K/V (bf16). MODE 1: fp32 linear epilogue to Cout.
template <int MODE>
__global__ __launch_bounds__(256, 2) void gemm_bt(
    const short* __restrict__ A, const short* __restrict__ Bm,
    const float* __restrict__ bias, float* __restrict__ Cout,
    short* __restrict__ Qb, short* __restrict__ Kb, short* __restrict__ Vb,
    int M, int N, int K) {
    __shared__ short As[128 * 32];
    __shared__ short Bs[128 * 32];
    const int tid = threadIdx.x;
    const int wave = tid >> 6, lane = tid & 63;
    const int row16 = lane & 15, kgrp = lane >> 4;
    const int wm = (wave >> 1) * 64, wn = (wave & 1) * 64;
    const int bm = blockIdx.y, bn = blockIdx.x;
    const short* Ab = A + (size_t)bm * 128 * K;
    const short* Bb = Bm + (size_t)bn * 128 * K;
    f32x4 acc[4][4] = {};
    const int r0 = tid >> 2;
    const int seg = (tid & 3) * 8;
    for (int k0 = 0; k0 < K; k0 += 32) {
        gld_lds16(Ab + (size_t)r0 * K + k0 + seg, &As[r0 * 32 + seg]);
        gld_lds16(Ab + (size_t)(r0 + 64) * K + k0 + seg, &As[(r0 + 64) * 32 + seg]);
        gld_lds16(Bb + (size_t)r0 * K + k0 + seg, &Bs[r0 * 32 + seg]);
        gld_lds16(Bb + (size_t)(r0 + 64) * K + k0 + seg, &Bs[(r0 + 64) * 32 + seg]);
        __syncthreads();
        short8 af[4], bfr[4];
#pragma unroll
        for (int i = 0; i < 4; ++i)
            af[i] = *(const short8*)&As[(wm + i * 16 + row16) * 32 + kgrp * 8];
#pragma unroll
        for (int j = 0; j < 4; ++j)
            bfr[j] = *(const short8*)&Bs[(wn + j * 16 + row16) * 32 + kgrp * 8];
#pragma unroll
        for (int i = 0; i < 4; ++i)
#pragma unroll
            for (int j = 0; j < 4; ++j)
                acc[i][j] = __builtin_amdgcn_mfma_f32_16x16x32_bf16(
                    af[i], bfr[j], acc[i][j], 0, 0, 0);
        __syncthreads();
    }
    // epilogue: C layout col = lane&15, row = (lane>>4)*4 + reg  [m89-verified]
#pragma unroll
    for (int j = 0; j < 4; ++j) {
        int gcol = bn * 128 + wn + j * 16 + row16;
        float bv = bias[gcol];
#pragma unroll
        for (int i = 0; i < 4; ++i) {
#pragma unroll
            for (int r = 0; r < 4; ++r) {
                int grow = bm * 128 + wm + i * 16 + kgrp * 4 + r;
                float val = acc[i][j][r] + bv;
                if (MODE == 1) {
                    Cout[(size_t)grow * N + gcol] = val;
                } else {
                    // grow = b*2048 + s_orig ; gcol = j channel of 3072
                    int b = grow >> 11, so = grow & 2047;
                    int hh = so >> 7, a = so & 127;
                    int rr = gcol / 192, cc = gcol - rr * 192;
                    int ss = a * 16 + rr;
                    size_t base = (((size_t)(b * H_N + hh)) * S_SZ + ss) * DK;
                    short bvv = f2bf(val);
                    if (cc < 64)       Qb[base + cc]       = bvv;
                    else if (cc < 128) Kb[base + cc - 64]  = bvv;
                    else               Vb[base + cc - 128] = bvv;
                }
            }
        }
    }
}

// ---------------- Flash attention: 64 (b,h) problems, S=2048, d=64 ----------------
// Block: 4 waves; wave owns 16 Q rows; KV tile = 64, staged in LDS (+8 pad).
__global__ __launch_bounds__(256, 2) void attn_kernel(
    const short* __restrict__ Q, const short* __restrict__ Kg,
    const short* __restrict__ Vg, short* __restrict__ O) {
    __shared__ short Ks[64 * 72];
    __shared__ short VTs[64 * 72];
    __shared__ short Ps[4][16 * 72];
    const int tid = threadIdx.x;
    const int wave = tid >> 6, lane = tid & 63;
    const int row16 = lane & 15, kgrp = lane >> 4;
    const int qt = blockIdx.x;   // 0..31
    const int bh = blockIdx.y;   // 0..63
    const int b = bh >> 4, h = bh & 15;
    const short* Qp = Q + (size_t)bh * S_SZ * DK;
    const short* Kp = Kg + (size_t)bh * S_SZ * DK;
    const short* Vp = Vg + (size_t)bh * S_SZ * DK;
    const int q0 = qt * 64 + wave * 16;

    short8 qf[2];
#pragma unroll
    for (int kc = 0; kc < 2; ++kc)
        qf[kc] = *(const short8*)&Qp[(size_t)(q0 + row16) * DK + kc * 32 + kgrp * 8];

    f32x4 oacc[4] = {};
    float m_run[4], l_run[4];
#pragma unroll
    for (int r = 0; r < 4; ++r) { m_run[r] = -1e30f; l_run[r] = 0.f; }

    const int sr = tid >> 3;         // 0..31
    const int sc = (tid & 7) * 8;    // 0..56

    for (int kv0 = 0; kv0 < S_SZ; kv0 += 64) {
        // stage K row-major (padded) and V transposed (padded)
#pragma unroll
        for (int it = 0; it < 2; ++it) {
            int r = sr + it * 32;
            short8 kv8 = *(const short8*)&Kp[(size_t)(kv0 + r) * DK + sc];
            *(short8*)&Ks[r * 72 + sc] = kv8;
            short8 vv8 = *(const short8*)&Vp[(size_t)(kv0 + r) * DK + sc];
#pragma unroll
            for (int e = 0; e < 8; ++e) VTs[(sc + e) * 72 + r] = vv8[e];
        }
        __syncthreads();

        // S = Q * K^T  (16 x 64 per wave)
        f32x4 sfr[4];
#pragma unroll
        for (int n = 0; n < 4; ++n) {
            sfr[n] = (f32x4){0.f, 0.f, 0.f, 0.f};
#pragma unroll
            for (int kc = 0; kc < 2; ++kc) {
                short8 kf = *(const short8*)&Ks[(n * 16 + row16) * 72 + kc * 32 + kgrp * 8];
                sfr[n] = __builtin_amdgcn_mfma_f32_16x16x32_bf16(qf[kc], kf, sfr[n], 0, 0, 0);
            }
        }
#pragma unroll
        for (int n = 0; n < 4; ++n)
#pragma unroll
            for (int r = 0; r < 4; ++r) sfr[n][r] *= 0.125f;

        // online softmax (row = (lane>>4)*4 + r, cols across lane&15 and the 4 n-frags)
        float corr[4];
#pragma unroll
        for (int r = 0; r < 4; ++r) {
            float mr = fmaxf(fmaxf(sfr[0][r], sfr[1][r]), fmaxf(sfr[2][r], sfr[3][r]));
            mr = fmaxf(mr, __shfl_xor(mr, 1));
            mr = fmaxf(mr, __shfl_xor(mr, 2));
            mr = fmaxf(mr, __shfl_xor(mr, 4));
            mr = fmaxf(mr, __shfl_xor(mr, 8));
            float mnew = fmaxf(m_run[r], mr);
            corr[r] = __expf(m_run[r] - mnew);
            m_run[r] = mnew;
            l_run[r] *= corr[r];
        }
#pragma unroll
        for (int n = 0; n < 4; ++n)
#pragma unroll
            for (int r = 0; r < 4; ++r) oacc[n][r] *= corr[r];

        float psum[4] = {0.f, 0.f, 0.f, 0.f};
#pragma unroll
        for (int n = 0; n < 4; ++n)
#pragma unroll
            for (int r = 0; r < 4; ++r) {
                float p = __expf(sfr[n][r] - m_run[r]);
                sfr[n][r] = p;
                psum[r] += p;
            }
#pragma unroll
        for (int r = 0; r < 4; ++r) {
            float ps = psum[r];
            ps += __shfl_xor(ps, 1);
            ps += __shfl_xor(ps, 2);
            ps += __shfl_xor(ps, 4);
            ps += __shfl_xor(ps, 8);
            l_run[r] += ps;
        }

        // P -> LDS (bf16, per-wave buffer), read back as MFMA A-fragments
#pragma unroll
        for (int n = 0; n < 4; ++n)
#pragma unroll
            for (int r = 0; r < 4; ++r)
                Ps[wave][(kgrp * 4 + r) * 72 + n * 16 + row16] = f2bf(sfr[n][r]);

        short8 pf[2];
#pragma unroll
        for (int kc = 0; kc < 2; ++kc)
            pf[kc] = *(const short8*)&Ps[wave][row16 * 72 + kc * 32 + kgrp * 8];

        // O += P * V   (V consumed via transposed LDS tile)
#pragma unroll
        for (int n = 0; n < 4; ++n)
#pragma unroll
            for (int kc = 0; kc < 2; ++kc) {
                short8 vf = *(const short8*)&VTs[(n * 16 + row16) * 72 + kc * 32 + kgrp * 8];
                oacc[n] = __builtin_amdgcn_mfma_f32_16x16x32_bf16(pf[kc], vf, oacc[n], 0, 0, 0);
            }
        __syncthreads();
    }

    // epilogue: O[b][ss][h*64+d] bf16 for the final GEMM
#pragma unroll
    for (int r = 0; r < 4; ++r) {
        float inv = 1.f / l_run[r];
        int row = q0 + kgrp * 4 + r;
#pragma unroll
        for (int n = 0; n < 4; ++n)
            O[((size_t)b * S_SZ + row) * MODEL + h * DK + n * 16 + row16] =
                f2bf(oacc[n][r] * inv);
    }
}

extern "C" void kernel_launch(void* const* d_in, const int* in_sizes, int n_in,
                              void* d_out, int out_size, void* d_ws, size_t ws_size,
                              hipStream_t stream) {
    const float* x    = (const float*)d_in[0];
    const float* Wqkv = (const float*)d_in[1];
    const float* bqkv = (const float*)d_in[2];
    const float* Wo   = (const float*)d_in[3];
    const float* bo   = (const float*)d_in[4];
    float* out = (float*)d_out;
    char* ws = (char*)d_ws;

    // workspace layout (bytes); Ob aliases xb (xb dead after gemm1)
    short* xb  = (short*)(ws + 0);           // 16 MiB
    short* wqb = (short*)(ws + 16777216);    //  6 MiB
    short* wob = (short*)(ws + 23068672);    //  2 MiB
    short* Qb  = (short*)(ws + 25165824);    // 16 MiB
    short* Kb  = (short*)(ws + 41943040);    // 16 MiB
    short* Vb  = (short*)(ws + 58720256);    // 16 MiB  (end: 75497472 = 72 MiB)
    short* Ob  = (short*)(ws + 0);           // aliases xb

    cvt_kernel<<<dim3(2048), dim3(256), 0, stream>>>(x, Wqkv, Wo, xb, wqb, wob);
    gemm_bt<0><<<dim3(QKV_DIM / 128, M_ROWS / 128), dim3(256), 0, stream>>>(
        xb, wqb, bqkv, nullptr, Qb, Kb, Vb, M_ROWS, QKV_DIM, IN_DIM);
    attn_kernel<<<dim3(S_SZ / 64, B_SZ * H_N), dim3(256), 0, stream>>>(Qb, Kb, Vb, Ob);
    gemm_bt<1><<<dim3(MODEL / 128, M_ROWS / 128), dim3(256), 0, stream>>>(
        Ob, wob, bo, out, nullptr, nullptr, nullptr, M_ROWS, MODEL, IN_DIM);
}

// Round 2
// 273.622 us; speedup vs baseline: 1.5943x; 1.5943x over previous
//
#include <hip/hip_runtime.h>
#include <stdint.h>

// MultiHeadAttention: x(4,2048,1024) fp32; W_qkv(3072,1024); b_qkv(3072); W_o(1024,1024); b_o(1024)
// Reference does h.reshape(B,16,S,192) DIRECTLY (no transpose):
//   h[b,hh,ss,cc] = linear[b, s_orig = hh*128 + ss/16, j = (ss%16)*192 + cc]
// Pipeline: cvt(fp32->bf16) -> gemm_bt<QKV scatter (Q pre-scaled by 1/8, V transposed)> ->
//           swapped 32x32 flash attn (in-register softmax, T12 lane-swap P, T2 swizzled LDS) ->
//           gemm_bt<out fp32>

typedef __attribute__((ext_vector_type(8))) short short8;
typedef __attribute__((ext_vector_type(4))) short short4v;
typedef __attribute__((ext_vector_type(4))) float f32x4;
typedef __attribute__((ext_vector_type(16))) float f32x16;

#define B_SZ 4
#define S_SZ 2048
#define H_N 16
#define DK 64
#define IN_DIM 1024
#define QKV_DIM 3072
#define MODEL 1024
#define M_ROWS (B_SZ * S_SZ)   // 8192

__device__ __forceinline__ short f2bf(float f) {
    union { float f; uint32_t u; } v; v.f = f;
    uint32_t r = v.u + 0x7FFFu + ((v.u >> 16) & 1u);
    return (short)(r >> 16);
}

__device__ __forceinline__ uint32_t pk2(float a, float b) {
    return (uint32_t)(uint16_t)f2bf(a) | ((uint32_t)(uint16_t)f2bf(b) << 16);
}

__device__ __forceinline__ void gld_lds16(const void* g, void* l) {
    __builtin_amdgcn_global_load_lds(
        (const __attribute__((address_space(1))) void*)g,
        (__attribute__((address_space(3))) void*)l, 16, 0, 0);
}

// ---------------- fp32 -> bf16 conversion of x, W_qkv, W_o ----------------
__global__ __launch_bounds__(256) void cvt_kernel(
    const float* __restrict__ x, const float* __restrict__ wq,
    const float* __restrict__ wo, short* __restrict__ xb,
    short* __restrict__ wqb, short* __restrict__ wob) {
    const int NX = M_ROWS * IN_DIM / 4;
    const int NQ = QKV_DIM * IN_DIM / 4;
    const int NO = MODEL * IN_DIM / 4;
    const int total = NX + NQ + NO;
    for (int i = blockIdx.x * blockDim.x + threadIdx.x; i < total;
         i += gridDim.x * blockDim.x) {
        const f32x4* src; short4v* dst; int j;
        if (i < NX)           { src = (const f32x4*)x;  dst = (short4v*)xb;  j = i; }
        else if (i < NX + NQ) { src = (const f32x4*)wq; dst = (short4v*)wqb; j = i - NX; }
        else                  { src = (const f32x4*)wo; dst = (short4v*)wob; j = i - NX - NQ; }
        f32x4 v = src[j];
        short4v o;
        o[0] = f2bf(v[0]); o[1] = f2bf(v[1]); o[2] = f2bf(v[2]); o[3] = f2bf(v[3]);
        dst[j] = o;
    }
}

// ---------------- GEMM C = A(MxK) * B(NxK)^T + bias  (bf16 in, m97-style) ----------------
// MODE 0: scatter epilogue into Q (scaled 1/8) / K / Vt (transposed). MODE 1: fp32 epilogue.
template <int MODE>
__global__ __launch_bounds__(256, 2) void gemm_bt(
    const short* __restrict__ A, const short* __restrict__ Bm,
    const float* __restrict__ bias, float* __restrict__ Cout,
    short* __restrict__ Qb, short* __restrict__ Kb, short* __restrict__ Vt,
    int M, int N, int K) {
    __shared__ short As[128 * 32];
    __shared__ short Bs[128 * 32];
    const int tid = threadIdx.x;
    const int wave = tid >> 6, lane = tid & 63;
    const int row16 = lane & 15, kgrp = lane >> 4;
    const int wm = (wave >> 1) * 64, wn = (wave & 1) * 64;
    const int bm = blockIdx.y, bn = blockIdx.x;
    const short* Ab = A + (size_t)bm * 128 * K;
    const short* Bb = Bm + (size_t)bn * 128 * K;
    f32x4 acc[4][4] = {};
    const int r0 = tid >> 2;
    const int seg = (tid & 3) * 8;
    for (int k0 = 0; k0 < K; k0 += 32) {
        gld_lds16(Ab + (size_t)r0 * K + k0 + seg, &As[r0 * 32 + seg]);
        gld_lds16(Ab + (size_t)(r0 + 64) * K + k0 + seg, &As[(r0 + 64) * 32 + seg]);
        gld_lds16(Bb + (size_t)r0 * K + k0 + seg, &Bs[r0 * 32 + seg]);
        gld_lds16(Bb + (size_t)(r0 + 64) * K + k0 + seg, &Bs[(r0 + 64) * 32 + seg]);
        __syncthreads();
        short8 af[4], bfr[4];
#pragma unroll
        for (int i = 0; i < 4; ++i)
            af[i] = *(const short8*)&As[(wm + i * 16 + row16) * 32 + kgrp * 8];
#pragma unroll
        for (int j = 0; j < 4; ++j)
            bfr[j] = *(const short8*)&Bs[(wn + j * 16 + row16) * 32 + kgrp * 8];
#pragma unroll
        for (int i = 0; i < 4; ++i)
#pragma unroll
            for (int j = 0; j < 4; ++j)
                acc[i][j] = __builtin_amdgcn_mfma_f32_16x16x32_bf16(
                    af[i], bfr[j], acc[i][j], 0, 0, 0);
        __syncthreads();
    }
#pragma unroll
    for (int j = 0; j < 4; ++j) {
        int gcol = bn * 128 + wn + j * 16 + row16;
        float bv = bias[gcol];
#pragma unroll
        for (int i = 0; i < 4; ++i) {
#pragma unroll
            for (int r = 0; r < 4; ++r) {
                int grow = bm * 128 + wm + i * 16 + kgrp * 4 + r;
                float val = acc[i][j][r] + bv;
                if (MODE == 1) {
                    Cout[(size_t)grow * N + gcol] = val;
                } else {
                    int b = grow >> 11, so = grow & 2047;
                    int hh = so >> 7, a = so & 127;
                    int rr = gcol / 192, cc = gcol - rr * 192;
                    int ss = a * 16 + rr;
                    int bh = b * H_N + hh;
                    if (cc < 64) {
                        Qb[(((size_t)bh) * S_SZ + ss) * DK + cc] = f2bf(val * 0.125f);
                    } else if (cc < 128) {
                        Kb[(((size_t)bh) * S_SZ + ss) * DK + cc - 64] = f2bf(val);
                    } else {
                        // V stored TRANSPOSED: Vt[bh][d][s]
                        Vt[((size_t)bh * DK + (cc - 128)) * S_SZ + ss] = f2bf(val);
                    }
                }
            }
        }
    }
}

// ---------------- Swapped 32x32 flash attention ----------------
// 4 waves/block, wave owns 32 q rows; KVBLK=64 double-buffered in LDS (XOR-swizzled).
// ST[kv][q] = mfma(K, Q); softmax in-register (lane = one q col);
// OT[d][q] = mfma(Vt, P); P redistributed via 2x shfl_xor(32) per 16-k chunk.
__global__ __launch_bounds__(256, 3) void attn_kernel(
    const short* __restrict__ Qg, const short* __restrict__ Kg,
    const short* __restrict__ Vtg, short* __restrict__ O) {
    __shared__ short Ks[2][64 * 64];
    __shared__ short Vs[2][64 * 64];
    const int tid = threadIdx.x;
    const int wave = tid >> 6, lane = tid & 63;
    const int q = lane & 31, hi = lane >> 5;
    const int bh = blockIdx.y;
    const int b = bh >> 4, h = bh & 15;
    const short* Qp = Qg + (size_t)bh * S_SZ * DK;
    const short* Kp = Kg + (size_t)bh * S_SZ * DK;
    const short* Vp = Vtg + (size_t)bh * DK * S_SZ;
    const int q0 = blockIdx.x * 128 + wave * 32;

    // Q B-fragments (Q pre-scaled by 1/8 in gemm1): qf[c][e] = Q[q][c*16 + hi*8 + e]
    short8 qf[4];
#pragma unroll
    for (int c = 0; c < 4; ++c)
        qf[c] = *(const short8*)&Qp[(size_t)(q0 + q) * DK + c * 16 + hi * 8];

    f32x16 ot0 = {}, ot1 = {};
    float m_run = -1e30f, l_run = 0.f;

    // staging: thread t covers row sr = t>>2, 16B chunks j = (t&3) and (t&3)+4
    const int sr = tid >> 2;
    const int sj = tid & 3;
    short8 kreg[2], vreg[2];

#define LOADT(KV0)                                                             \
    {                                                                          \
        _Pragma("unroll") for (int it = 0; it < 2; ++it) {                     \
            int j = sj + 4 * it;                                               \
            kreg[it] = *(const short8*)&Kp[(size_t)((KV0) + sr) * DK + j * 8]; \
            vreg[it] = *(const short8*)&Vp[(size_t)sr * S_SZ + (KV0) + j * 8]; \
        }                                                                      \
    }
#define WRITET(BUF)                                                            \
    {                                                                          \
        _Pragma("unroll") for (int it = 0; it < 2; ++it) {                     \
            int j = sj + 4 * it;                                               \
            int off = sr * 64 + ((j * 8) ^ ((sr & 7) << 3));                   \
            *(short8*)&Ks[BUF][off] = kreg[it];                                \
            *(short8*)&Vs[BUF][off] = vreg[it];                                \
        }                                                                      \
    }

    LOADT(0);
    WRITET(0);

    const int NT = S_SZ / 64;  // 32
    for (int t = 0; t < NT; ++t) {
        __syncthreads();
        const int cur = t & 1;
        const bool pf = (t + 1) < NT;
        if (pf) LOADT((t + 1) * 64);

        // ---- ST = K * Q^T : two 32-kv subtiles ----
        f32x16 st0 = {}, st1 = {};
#pragma unroll
        for (int c = 0; c < 4; ++c) {
            short8 kf0 = *(const short8*)&Ks[cur][q * 64 +
                             ((c * 16 + hi * 8) ^ ((q & 7) << 3))];
            short8 kf1 = *(const short8*)&Ks[cur][(32 + q) * 64 +
                             ((c * 16 + hi * 8) ^ (((32 + q) & 7) << 3))];
            st0 = __builtin_amdgcn_mfma_f32_32x32x16_bf16(kf0, qf[c], st0, 0, 0, 0);
            st1 = __builtin_amdgcn_mfma_f32_32x32x16_bf16(kf1, qf[c], st1, 0, 0, 0);
        }

        // ---- online softmax (lane owns col q; kv half per hi) ----
        float pm = st0[0];
#pragma unroll
        for (int r = 1; r < 16; ++r) pm = fmaxf(pm, st0[r]);
#pragma unroll
        for (int r = 0; r < 16; ++r) pm = fmaxf(pm, st1[r]);
        pm = fmaxf(pm, __shfl_xor(pm, 32));
        float mnew = fmaxf(m_run, pm);
        float corr = __expf(m_run - mnew);
        m_run = mnew;
        float ssum = 0.f;
#pragma unroll
        for (int r = 0; r < 16; ++r) { st0[r] = __expf(st0[r] - mnew); ssum += st0[r]; }
#pragma unroll
        for (int r = 0; r < 16; ++r) { st1[r] = __expf(st1[r] - mnew); ssum += st1[r]; }
        ssum += __shfl_xor(ssum, 32);
        l_run = l_run * corr + ssum;
#pragma unroll
        for (int r = 0; r < 16; ++r) { ot0[r] *= corr; ot1[r] *= corr; }

        // ---- PV: per 16-kv chunk, build P B-frag via lane<->lane+32 swap ----
#define PVCHUNK(ST, B0, CH)                                                    \
    {                                                                          \
        uint32_t A0 = pk2(ST[(B0) + 0], ST[(B0) + 1]);                         \
        uint32_t A1 = pk2(ST[(B0) + 2], ST[(B0) + 3]);                         \
        uint32_t B0w = pk2(ST[(B0) + 4], ST[(B0) + 5]);                        \
        uint32_t B1w = pk2(ST[(B0) + 6], ST[(B0) + 7]);                        \
        uint32_t s0 = hi ? A0 : B0w, s1 = hi ? A1 : B1w;                       \
        uint32_t r0 = (uint32_t)__shfl_xor((int)s0, 32);                       \
        uint32_t r1 = (uint32_t)__shfl_xor((int)s1, 32);                       \
        union { uint32_t u[4]; short8 s8; } pbu;                               \
        pbu.u[0] = hi ? r0 : A0;                                               \
        pbu.u[1] = hi ? r1 : A1;                                               \
        pbu.u[2] = hi ? B0w : r0;                                              \
        pbu.u[3] = hi ? B1w : r1;                                              \
        short8 vf0 = *(const short8*)&Vs[cur][q * 64 +                         \
                         (((CH) * 16 + hi * 8) ^ ((q & 7) << 3))];             \
        short8 vf1 = *(const short8*)&Vs[cur][(32 + q) * 64 +                  \
                         (((CH) * 16 + hi * 8) ^ (((32 + q) & 7) << 3))];      \
        ot0 = __builtin_amdgcn_mfma_f32_32x32x16_bf16(vf0, pbu.s8, ot0, 0, 0, 0); \
        ot1 = __builtin_amdgcn_mfma_f32_32x32x16_bf16(vf1, pbu.s8, ot1, 0, 0, 0); \
    }
        PVCHUNK(st0, 0, 0);
        PVCHUNK(st0, 8, 1);
        PVCHUNK(st1, 0, 2);
        PVCHUNK(st1, 8, 3);
#undef PVCHUNK

        if (pf) WRITET(cur ^ 1);
    }

    // ---- epilogue: O[b][s][h*64+d] = OT[d][q] / l ----
    float inv = 1.f / l_run;
    size_t rowbase = ((size_t)b * S_SZ + (q0 + q)) * MODEL + h * DK;
#pragma unroll
    for (int i = 0; i < 4; ++i) {
        short4v v0, v1;
#pragma unroll
        for (int jj = 0; jj < 4; ++jj) {
            v0[jj] = f2bf(ot0[4 * i + jj] * inv);
            v1[jj] = f2bf(ot1[4 * i + jj] * inv);
        }
        *(short4v*)&O[rowbase + 8 * i + 4 * hi] = v0;
        *(short4v*)&O[rowbase + 32 + 8 * i + 4 * hi] = v1;
    }
#undef LOADT
#undef WRITET
}

extern "C" void kernel_launch(void* const* d_in, const int* in_sizes, int n_in,
                              void* d_out, int out_size, void* d_ws, size_t ws_size,
                              hipStream_t stream) {
    const float* x    = (const float*)d_in[0];
    const float* Wqkv = (const float*)d_in[1];
    const float* bqkv = (const float*)d_in[2];
    const float* Wo   = (const float*)d_in[3];
    const float* bo   = (const float*)d_in[4];
    float* out = (float*)d_out;
    char* ws = (char*)d_ws;

    short* xb  = (short*)(ws + 0);           // 16 MiB
    short* wqb = (short*)(ws + 16777216);    //  6 MiB
    short* wob = (short*)(ws + 23068672);    //  2 MiB
    short* Qb  = (short*)(ws + 25165824);    // 16 MiB
    short* Kb  = (short*)(ws + 41943040);    // 16 MiB
    short* Vt  = (short*)(ws + 58720256);    // 16 MiB (transposed [bh][d][s])
    short* Ob  = (short*)(ws + 0);           // aliases xb (dead after gemm1)

    cvt_kernel<<<dim3(2048), dim3(256), 0, stream>>>(x, Wqkv, Wo, xb, wqb, wob);
    gemm_bt<0><<<dim3(QKV_DIM / 128, M_ROWS / 128), dim3(256), 0, stream>>>(
        xb, wqb, bqkv, nullptr, Qb, Kb, Vt, M_ROWS, QKV_DIM, IN_DIM);
    attn_kernel<<<dim3(S_SZ / 128, B_SZ * H_N), dim3(256), 0, stream>>>(Qb, Kb, Vt, Ob);
    gemm_bt<1><<<dim3(MODEL / 128, M_ROWS / 128), dim3(256), 0, stream>>>(
        Ob, wob, bo, out, nullptr, nullptr, nullptr, M_ROWS, MODEL, IN_DIM);
}